// Round 10
// baseline (233.719 us; speedup 1.0000x reference)
//
#include <hip/hip_runtime.h>

typedef __attribute__((ext_vector_type(8))) short bf16x8;
typedef __attribute__((ext_vector_type(4))) short bf16x4;
typedef __attribute__((ext_vector_type(4))) float f32x4;
typedef __attribute__((ext_vector_type(4))) float floatx4;

__device__ __forceinline__ unsigned short f2bf(float f) {
    unsigned int u = __float_as_uint(f);
    u += 0x7fffu + ((u >> 16) & 1u);   // round-to-nearest-even
    return (unsigned short)(u >> 16);
}
__device__ __forceinline__ float bf2f_s(short h) {
    return __uint_as_float(((unsigned int)(unsigned short)h) << 16);
}

// pack 8 f32 -> bf16x8 via HW packed convert (RNE)
__device__ __forceinline__ bf16x8 cvt8(f32x4 lo, f32x4 hi) {
    union { unsigned int u[4]; bf16x8 v; } r;
    asm("v_cvt_pk_bf16_f32 %0, %1, %2" : "=v"(r.u[0]) : "v"(lo[0]), "v"(lo[1]));
    asm("v_cvt_pk_bf16_f32 %0, %1, %2" : "=v"(r.u[1]) : "v"(lo[2]), "v"(lo[3]));
    asm("v_cvt_pk_bf16_f32 %0, %1, %2" : "=v"(r.u[2]) : "v"(hi[0]), "v"(hi[1]));
    asm("v_cvt_pk_bf16_f32 %0, %1, %2" : "=v"(r.u[3]) : "v"(hi[2]), "v"(hi[3]));
    return r.v;
}

// ---------------- kernel 0: Wo -> bf16 ----------------
__global__ void k_convert(const float* __restrict__ Wo, unsigned short* __restrict__ Wob) {
    int i = (blockIdx.x * blockDim.x + threadIdx.x) * 4;
    if (i < 131072) {
        floatx4 c = *reinterpret_cast<const floatx4*>(Wo + i);
        bf16x4 sc;
        #pragma unroll
        for (int e = 0; e < 4; ++e) sc[e] = (short)f2bf(c[e]);
        *reinterpret_cast<bf16x4*>(Wob + i) = sc;
    }
}

// ---------------- kernel 1: keys/vals GEMM (small blocks, many resident) ----------------
// kv[m][n] = sum_e patches[m][e] * bf16(W[n][e])  (+ patch_pos for n<128)
// 256 threads (4 waves), tile 64M x 128N, BK=64, grid 1568 (784 M-tiles x 2 N-halves).
// LDS 27.6 KB + modest VGPR -> 4-5 blocks resident per CU; cross-block phase offset
// hides load latency (the only mechanism that measured-ly works on this shape).
// B direct from Wk/Wv f32 (L2-resident); plain __syncthreads (proven R0 sync).
__global__ __launch_bounds__(256)
void k_keysvals(const float* __restrict__ patches,
                const float* __restrict__ Wk,
                const float* __restrict__ Wv,
                const float* __restrict__ patch_pos,
                unsigned short* __restrict__ kv)
{
    __shared__ unsigned short As[64][72];    // +8 pad: proven conflict-light layout
    __shared__ unsigned short Bs[128][72];

    const int tid  = threadIdx.x;
    const int lane = tid & 63;
    const int wave = tid >> 6;      // 0..3
    const int wm   = wave >> 1;     // 0..1 : 32-row half
    const int wn   = wave & 1;      // 0..1 : 64-col half
    const int l15  = lane & 15;
    const int lg   = lane >> 4;     // 0..3

    const int mt   = blockIdx.x >> 1;
    const int nb   = blockIdx.x & 1;       // 0 -> Wk (keys), 1 -> Wv (vals)
    const int row0 = mt * 64;
    const float* wsrc = nb ? Wv : Wk;      // 128 rows x 1024

    // A staging: thread -> (row ar, 16-float chunk ac)
    const int ar = tid >> 2;               // 0..63
    const int ac = (tid & 3) * 16;         // 0..48
    // B staging: thread -> (row br, 32-float half bc)
    const int br = tid >> 1;               // 0..127
    const int bc = (tid & 1) * 32;         // 0 or 32

    f32x4 acc[2][4];
    #pragma unroll
    for (int i = 0; i < 2; ++i)
        #pragma unroll
        for (int j = 0; j < 4; ++j)
            acc[i][j] = (f32x4){0.f, 0.f, 0.f, 0.f};

    for (int ko = 0; ko < 1024; ko += 64) {
        // stage A: 64x64 f32 -> bf16
        {
            const float* p = patches + (size_t)(row0 + ar) * 1024 + ko + ac;
            f32x4 v0 = *reinterpret_cast<const f32x4*>(p);
            f32x4 v1 = *reinterpret_cast<const f32x4*>(p + 4);
            f32x4 v2 = *reinterpret_cast<const f32x4*>(p + 8);
            f32x4 v3 = *reinterpret_cast<const f32x4*>(p + 12);
            *reinterpret_cast<bf16x8*>(&As[ar][ac])     = cvt8(v0, v1);
            *reinterpret_cast<bf16x8*>(&As[ar][ac + 8]) = cvt8(v2, v3);
        }
        // stage B: 128x64 f32 -> bf16
        {
            const float* p = wsrc + (size_t)br * 1024 + ko + bc;
            f32x4 v0 = *reinterpret_cast<const f32x4*>(p);
            f32x4 v1 = *reinterpret_cast<const f32x4*>(p + 4);
            f32x4 v2 = *reinterpret_cast<const f32x4*>(p + 8);
            f32x4 v3 = *reinterpret_cast<const f32x4*>(p + 12);
            f32x4 v4 = *reinterpret_cast<const f32x4*>(p + 16);
            f32x4 v5 = *reinterpret_cast<const f32x4*>(p + 20);
            f32x4 v6 = *reinterpret_cast<const f32x4*>(p + 24);
            f32x4 v7 = *reinterpret_cast<const f32x4*>(p + 28);
            *reinterpret_cast<bf16x8*>(&Bs[br][bc])      = cvt8(v0, v1);
            *reinterpret_cast<bf16x8*>(&Bs[br][bc + 8])  = cvt8(v2, v3);
            *reinterpret_cast<bf16x8*>(&Bs[br][bc + 16]) = cvt8(v4, v5);
            *reinterpret_cast<bf16x8*>(&Bs[br][bc + 24]) = cvt8(v6, v7);
        }
        __syncthreads();
        #pragma unroll
        for (int kk = 0; kk < 2; ++kk) {
            bf16x8 af[2], bfr[4];
            #pragma unroll
            for (int mi = 0; mi < 2; ++mi)
                af[mi] = *reinterpret_cast<const bf16x8*>(&As[wm * 32 + mi * 16 + l15][kk * 32 + lg * 8]);
            #pragma unroll
            for (int ni = 0; ni < 4; ++ni)
                bfr[ni] = *reinterpret_cast<const bf16x8*>(&Bs[wn * 64 + ni * 16 + l15][kk * 32 + lg * 8]);
            #pragma unroll
            for (int mi = 0; mi < 2; ++mi)
                #pragma unroll
                for (int ni = 0; ni < 4; ++ni)
                    acc[mi][ni] = __builtin_amdgcn_mfma_f32_16x16x32_bf16(af[mi], bfr[ni], acc[mi][ni], 0, 0, 0);
        }
        __syncthreads();
    }

    // epilogue: C/D layout col=lane&15 (n), row=(lane>>4)*4+i (m)
    #pragma unroll
    for (int mi = 0; mi < 2; ++mi) {
        #pragma unroll
        for (int i = 0; i < 4; ++i) {
            int m  = row0 + wm * 32 + mi * 16 + lg * 4 + i;
            int kp = m % 196;
            #pragma unroll
            for (int ni = 0; ni < 4; ++ni) {
                int nl = wn * 64 + ni * 16 + l15;       // 0..127 within half
                int n  = nb * 128 + nl;
                float v = acc[mi][ni][i];
                if (nb == 0) v += patch_pos[kp * 128 + nl];
                kv[(size_t)m * 256 + n] = f2bf(v);
            }
        }
    }
}

// ---------------- kernel 2: per-batch attention ----------------
__global__ __launch_bounds__(1024)
void k_attn(const unsigned short* __restrict__ kv,
            const float* __restrict__ queries,
            const float* __restrict__ prior,
            const float* __restrict__ temperature,
            float* __restrict__ attn_out,
            unsigned short* __restrict__ att)
{
    __shared__ unsigned short k_s[196][136];
    __shared__ unsigned short v_s[196][128];
    __shared__ unsigned short q_s[52][128];
    __shared__ float          l_s[52][196];

    const int b   = blockIdx.x;
    const int tid = threadIdx.x;
    const size_t base = (size_t)b * 196 * 256;

    for (int idx = tid; idx < 6272; idx += 1024) {
        int row = idx >> 5;
        int c   = (idx & 31) * 8;
        bf16x8 v = *reinterpret_cast<const bf16x8*>(kv + base + row * 256 + c);
        if (c < 128) *reinterpret_cast<bf16x8*>(&k_s[row][c])       = v;
        else         *reinterpret_cast<bf16x8*>(&v_s[row][c - 128]) = v;
    }
    for (int idx = tid; idx < 1664; idx += 1024) {
        int row = idx >> 5;
        int c   = (idx & 31) * 4;
        const float* qp = queries + row * 128 + c;
        bf16x4 sv;
        sv[0] = (short)f2bf(qp[0]); sv[1] = (short)f2bf(qp[1]);
        sv[2] = (short)f2bf(qp[2]); sv[3] = (short)f2bf(qp[3]);
        *reinterpret_cast<bf16x4*>(&q_s[row][c]) = sv;
    }
    __syncthreads();

    const float inv_temp  = 1.0f / (log1pf(expf(temperature[0])) + 0.5f);
    const float inv_scale = 0.08838834764831845f;

    for (int task = tid; task < 3328; task += 1024) {
        int q  = task >> 6;
        int kg = task & 63;
        if (kg < 49) {
            float dot0 = 0.f, dot1 = 0.f, dot2 = 0.f, dot3 = 0.f;
            #pragma unroll 4
            for (int c = 0; c < 128; c += 8) {
                bf16x8 qv = *reinterpret_cast<const bf16x8*>(&q_s[q][c]);
                float qf[8];
                #pragma unroll
                for (int e = 0; e < 8; ++e) qf[e] = bf2f_s(qv[e]);
                bf16x8 k0v = *reinterpret_cast<const bf16x8*>(&k_s[kg][c]);
                bf16x8 k1v = *reinterpret_cast<const bf16x8*>(&k_s[kg + 49][c]);
                bf16x8 k2v = *reinterpret_cast<const bf16x8*>(&k_s[kg + 98][c]);
                bf16x8 k3v = *reinterpret_cast<const bf16x8*>(&k_s[kg + 147][c]);
                #pragma unroll
                for (int e = 0; e < 8; ++e) {
                    dot0 += qf[e] * bf2f_s(k0v[e]);
                    dot1 += qf[e] * bf2f_s(k1v[e]);
                    dot2 += qf[e] * bf2f_s(k2v[e]);
                    dot3 += qf[e] * bf2f_s(k3v[e]);
                }
            }
            int k;
            k = kg;       l_s[q][k] = (dot0 * inv_scale + prior[q * 196 + k]) * inv_temp;
            k = kg + 49;  l_s[q][k] = (dot1 * inv_scale + prior[q * 196 + k]) * inv_temp;
            k = kg + 98;  l_s[q][k] = (dot2 * inv_scale + prior[q * 196 + k]) * inv_temp;
            k = kg + 147; l_s[q][k] = (dot3 * inv_scale + prior[q * 196 + k]) * inv_temp;
        }
    }
    __syncthreads();

    const int lane = tid & 63;
    const int wave = tid >> 6;
    for (int q = wave; q < 52; q += 16) {
        float x0 = l_s[q][lane];
        float x1 = l_s[q][lane + 64];
        float x2 = l_s[q][lane + 128];
        float x3 = (lane < 4) ? l_s[q][lane + 192] : -1e30f;
        float m = fmaxf(fmaxf(x0, x1), fmaxf(x2, x3));
        #pragma unroll
        for (int off = 32; off > 0; off >>= 1) m = fmaxf(m, __shfl_xor(m, off));
        float e0 = expf(x0 - m), e1 = expf(x1 - m), e2 = expf(x2 - m);
        float e3 = (lane < 4) ? expf(x3 - m) : 0.0f;
        float s = e0 + e1 + e2 + e3;
        #pragma unroll
        for (int off = 32; off > 0; off >>= 1) s += __shfl_xor(s, off);
        float inv = 1.0f / s;
        float* po = attn_out + ((size_t)b * 52 + q) * 196;
        float a0 = e0 * inv, a1 = e1 * inv, a2 = e2 * inv;
        l_s[q][lane]       = a0;  po[lane]       = a0;
        l_s[q][lane + 64]  = a1;  po[lane + 64]  = a1;
        l_s[q][lane + 128] = a2;  po[lane + 128] = a2;
        if (lane < 4) { float a3 = e3 * inv; l_s[q][lane + 192] = a3; po[lane + 192] = a3; }
    }
    __syncthreads();

    if (tid < 832) {
        int q  = tid >> 4;
        int a0 = (tid & 15) * 8;
        float accv[8] = {0.f, 0.f, 0.f, 0.f, 0.f, 0.f, 0.f, 0.f};
        for (int k = 0; k < 196; ++k) {
            float w = l_s[q][k];
            bf16x8 vv = *reinterpret_cast<const bf16x8*>(&v_s[k][a0]);
            #pragma unroll
            for (int e = 0; e < 8; ++e) accv[e] += w * bf2f_s(vv[e]);
        }
        bf16x8 sv;
        #pragma unroll
        for (int e = 0; e < 8; ++e) sv[e] = (short)f2bf(accv[e]);
        *reinterpret_cast<bf16x8*>(att + ((size_t)b * 52 + q) * 128 + a0) = sv;
    }
}

// ---------------- kernel 3: output GEMM ----------------
__global__ __launch_bounds__(512)
void k_out(const unsigned short* __restrict__ att,
           const unsigned short* __restrict__ Wob,
           const float* __restrict__ bo,
           float* __restrict__ out)
{
    __shared__ unsigned short As[64][72];
    __shared__ unsigned short Bs[256][72];

    const int tid  = threadIdx.x;
    const int lane = tid & 63;
    const int wave = tid >> 6;
    const int wm   = wave >> 2;
    const int wn   = wave & 3;
    const int l15  = lane & 15;
    const int lg   = lane >> 4;
    const int row0 = blockIdx.x * 64;
    const int e0   = blockIdx.y * 256;

    f32x4 acc[2][4];
    #pragma unroll
    for (int i = 0; i < 2; ++i)
        #pragma unroll
        for (int j = 0; j < 4; ++j)
            acc[i][j] = (f32x4){0.f, 0.f, 0.f, 0.f};

    for (int ko = 0; ko < 128; ko += 64) {
        {
            int r = tid >> 3;
            int c = (tid & 7) * 8;
            bf16x8 v = *reinterpret_cast<const bf16x8*>(att + (size_t)(row0 + r) * 128 + ko + c);
            *reinterpret_cast<bf16x8*>(&As[r][c]) = v;
        }
        {
            int r = tid >> 3;
            int c = (tid & 7) * 8;
            #pragma unroll
            for (int it = 0; it < 4; ++it) {
                bf16x8 v = *reinterpret_cast<const bf16x8*>(Wob + (size_t)(e0 + it * 64 + r) * 128 + ko + c);
                *reinterpret_cast<bf16x8*>(&Bs[it * 64 + r][c]) = v;
            }
        }
        __syncthreads();
        #pragma unroll
        for (int kk = 0; kk < 2; ++kk) {
            bf16x8 af[2], bfr[4];
            #pragma unroll
            for (int mi = 0; mi < 2; ++mi)
                af[mi] = *reinterpret_cast<const bf16x8*>(&As[wm * 32 + mi * 16 + l15][kk * 32 + lg * 8]);
            #pragma unroll
            for (int ni = 0; ni < 4; ++ni)
                bfr[ni] = *reinterpret_cast<const bf16x8*>(&Bs[wn * 64 + ni * 16 + l15][kk * 32 + lg * 8]);
            #pragma unroll
            for (int mi = 0; mi < 2; ++mi)
                #pragma unroll
                for (int ni = 0; ni < 4; ++ni)
                    acc[mi][ni] = __builtin_amdgcn_mfma_f32_16x16x32_bf16(af[mi], bfr[ni], acc[mi][ni], 0, 0, 0);
        }
        __syncthreads();
    }
    #pragma unroll
    for (int mi = 0; mi < 2; ++mi) {
        #pragma unroll
        for (int i = 0; i < 4; ++i) {
            int m = row0 + wm * 32 + mi * 16 + lg * 4 + i;
            #pragma unroll
            for (int ni = 0; ni < 4; ++ni) {
                int e = e0 + wn * 64 + ni * 16 + l15;
                out[(size_t)m * 1024 + e] = acc[mi][ni][i] + bo[e];
            }
        }
    }
}

extern "C" void kernel_launch(void* const* d_in, const int* in_sizes, int n_in,
                              void* d_out, int out_size, void* d_ws, size_t ws_size,
                              hipStream_t stream)
{
    const float* patches     = (const float*)d_in[0];   // [256][196][1024]
    const float* queries     = (const float*)d_in[1];   // [52][128]
    const float* Wk          = (const float*)d_in[2];   // [128][1024]
    const float* Wv          = (const float*)d_in[3];   // [128][1024]
    const float* Wo          = (const float*)d_in[4];   // [1024][128]
    const float* bo          = (const float*)d_in[5];   // [1024]
    const float* patch_pos   = (const float*)d_in[6];   // [196][128]
    const float* temperature = (const float*)d_in[7];   // [1]
    const float* prior       = (const float*)d_in[8];   // [52][196]

    float* out      = (float*)d_out;                    // [256*52][1024]
    float* attn_out = out + (size_t)256 * 52 * 1024;    // [256*52][196]

    unsigned short* Wob = (unsigned short*)d_ws;               // 1024*128
    unsigned short* kv  = Wob + 1024 * 128;                    // 50176*256
    unsigned short* att = kv + (size_t)50176 * 256;            // 13312*128

    k_convert <<<128, 256, 0, stream>>>(Wo, Wob);
    k_keysvals<<<1568, 256, 0, stream>>>(patches, Wk, Wv, patch_pos, kv);
    k_attn    <<<256, 1024, 0, stream>>>(kv, queries, prior, temperature, attn_out, att);
    k_out     <<<dim3(208, 4), 512, 0, stream>>>(att, Wob, bo, out);
}

// Round 11
// 145.812 us; speedup vs baseline: 1.6029x; 1.6029x over previous
//
#include <hip/hip_runtime.h>

typedef __attribute__((ext_vector_type(8))) short bf16x8;
typedef __attribute__((ext_vector_type(4))) short bf16x4;
typedef __attribute__((ext_vector_type(4))) float f32x4;
typedef __attribute__((ext_vector_type(4))) float floatx4;

__device__ __forceinline__ unsigned short f2bf(float f) {
    unsigned int u = __float_as_uint(f);
    u += 0x7fffu + ((u >> 16) & 1u);   // round-to-nearest-even
    return (unsigned short)(u >> 16);
}
__device__ __forceinline__ float bf2f_s(short h) {
    return __uint_as_float(((unsigned int)(unsigned short)h) << 16);
}

// pack 8 f32 -> bf16x8 via HW packed convert (RNE)
__device__ __forceinline__ bf16x8 cvt8(f32x4 lo, f32x4 hi) {
    union { unsigned int u[4]; bf16x8 v; } r;
    asm("v_cvt_pk_bf16_f32 %0, %1, %2" : "=v"(r.u[0]) : "v"(lo[0]), "v"(lo[1]));
    asm("v_cvt_pk_bf16_f32 %0, %1, %2" : "=v"(r.u[1]) : "v"(lo[2]), "v"(lo[3]));
    asm("v_cvt_pk_bf16_f32 %0, %1, %2" : "=v"(r.u[2]) : "v"(hi[0]), "v"(hi[1]));
    asm("v_cvt_pk_bf16_f32 %0, %1, %2" : "=v"(r.u[3]) : "v"(hi[2]), "v"(hi[3]));
    return r.v;
}
// pack 4 f32 -> bf16x4
__device__ __forceinline__ bf16x4 cvt4(f32x4 v) {
    union { unsigned int u[2]; bf16x4 x; } r;
    asm("v_cvt_pk_bf16_f32 %0, %1, %2" : "=v"(r.u[0]) : "v"(v[0]), "v"(v[1]));
    asm("v_cvt_pk_bf16_f32 %0, %1, %2" : "=v"(r.u[1]) : "v"(v[2]), "v"(v[3]));
    return r.x;
}

// ---------------- kernel 0: weight conversion to bf16 ----------------
// Wkvb[256][1024]: rows 0-127 = Wk, 128-255 = Wv.  Wob[1024][128] = Wo.
__global__ void k_convert(const float* __restrict__ Wk, const float* __restrict__ Wv,
                          const float* __restrict__ Wo,
                          unsigned short* __restrict__ Wkvb, unsigned short* __restrict__ Wob) {
    int i = (blockIdx.x * blockDim.x + threadIdx.x) * 4;
    if (i < 131072) {
        floatx4 a = *reinterpret_cast<const floatx4*>(Wk + i);
        floatx4 b = *reinterpret_cast<const floatx4*>(Wv + i);
        floatx4 c = *reinterpret_cast<const floatx4*>(Wo + i);
        *reinterpret_cast<bf16x4*>(Wkvb + i)          = cvt4(a);
        *reinterpret_cast<bf16x4*>(Wkvb + 131072 + i) = cvt4(b);
        *reinterpret_cast<bf16x4*>(Wob + i)           = cvt4(c);
    }
}

// ---------------- kernel 1: keys/vals GEMM (byte-minimal: 1 batch per block) ----------------
// kv[m][n] = sum_e patches[m][e] * Wkvb[n][e]  (+ patch_pos bias for n<128)
// Grid 256 = 1 block/CU exactly. Block owns batch b: A rows [196b,196b+196) read ONCE
// (205 MB total); B = Wkvb bf16 read once per block (128 MB total). Issued-byte floor
// ~53 us at the measured 6.5 TB/s per-CU load-path ceiling (the real limiter, R9).
// 512 thr, 8 waves, wave = 196M x 32N, acc[13][2]; frag 12 rows >=196 are garbage
// (uninit LDS) but MFMA is row-independent and those rows are never stored.
__global__ __launch_bounds__(512)
void k_keysvals(const float* __restrict__ patches,
                const unsigned short* __restrict__ Wkvb,
                const float* __restrict__ patch_pos,
                unsigned short* __restrict__ kv)
{
    __shared__ unsigned short As[2][208][72];   // rows 0..195 staged; +8 pad (2-way max)
    __shared__ unsigned short Bs[2][256][72];

    const int tid  = threadIdx.x;
    const int lane = tid & 63;
    const int w    = tid >> 6;       // 0..7 : 32-col N slice
    const int l15  = lane & 15;
    const int lg   = lane >> 4;      // 0..3
    const int b    = blockIdx.x;     // batch
    const float* abase = patches + (size_t)b * 196 * 1024;

    // B staging: 2 threads/row, 64B (32 bf16) each
    const int brow = tid >> 1;       // 0..255
    const int bh   = tid & 1;        // k-half of the 64-col tile
    const unsigned short* bgp = Wkvb + (size_t)brow * 1024 + bh * 32;

    f32x4  aH[7];                    // staged A (f32), 6 full + 1 cond granule
    bf16x8 bH[4];                    // staged B (already bf16)

    f32x4 acc[13][2];
    #pragma unroll
    for (int i = 0; i < 13; ++i) {
        acc[i][0] = (f32x4){0.f, 0.f, 0.f, 0.f};
        acc[i][1] = (f32x4){0.f, 0.f, 0.f, 0.f};
    }

    auto issue = [&](int t) {
        const int ko = t * 64;
        #pragma unroll
        for (int i = 0; i < 6; ++i) {
            int g = tid + i * 512;                 // granule id 0..3071
            int r = g >> 4, gc = g & 15;
            aH[i] = *reinterpret_cast<const f32x4*>(abase + (size_t)r * 1024 + ko + gc * 4);
        }
        if (tid < 64) {                            // granules 3072..3135 (rows 192..195)
            int g = 3072 + tid;
            int r = g >> 4, gc = g & 15;
            aH[6] = *reinterpret_cast<const f32x4*>(abase + (size_t)r * 1024 + ko + gc * 4);
        }
        #pragma unroll
        for (int j = 0; j < 4; ++j)
            bH[j] = *reinterpret_cast<const bf16x8*>(bgp + ko + j * 8);
    };
    auto store = [&](int buf) {
        #pragma unroll
        for (int i = 0; i < 6; ++i) {
            int g = tid + i * 512;
            int r = g >> 4, gc = g & 15;
            *reinterpret_cast<bf16x4*>(&As[buf][r][gc * 4]) = cvt4(aH[i]);
        }
        if (tid < 64) {
            int g = 3072 + tid;
            int r = g >> 4, gc = g & 15;
            *reinterpret_cast<bf16x4*>(&As[buf][r][gc * 4]) = cvt4(aH[6]);
        }
        #pragma unroll
        for (int j = 0; j < 4; ++j)
            *reinterpret_cast<bf16x8*>(&Bs[buf][brow][bh * 32 + j * 8]) = bH[j];
    };
    auto compute = [&](int buf) {
        #pragma unroll
        for (int kk = 0; kk < 2; ++kk) {
            bf16x8 bf[2];
            #pragma unroll
            for (int nf = 0; nf < 2; ++nf)
                bf[nf] = *reinterpret_cast<const bf16x8*>(&Bs[buf][w * 32 + nf * 16 + l15][kk * 32 + lg * 8]);
            #pragma unroll
            for (int mf = 0; mf < 13; ++mf) {
                bf16x8 af = *reinterpret_cast<const bf16x8*>(&As[buf][mf * 16 + l15][kk * 32 + lg * 8]);
                acc[mf][0] = __builtin_amdgcn_mfma_f32_16x16x32_bf16(af, bf[0], acc[mf][0], 0, 0, 0);
                acc[mf][1] = __builtin_amdgcn_mfma_f32_16x16x32_bf16(af, bf[1], acc[mf][1], 0, 0, 0);
            }
        }
    };

    // prologue: tile 0 staged to buf 0
    issue(0);
    store(0);
    __syncthreads();

    for (int t = 0; t < 16; ++t) {
        if (t < 15) issue(t + 1);        // global loads fly during compute
        compute(t & 1);
        if (t < 15) store((t + 1) & 1);  // waits loads, converts, writes other buf
        __syncthreads();                 // one barrier per step (dbuf-safe)
    }

    // epilogue: C/D layout col=lane&15 (n), row=(lane>>4)*4+i (m local)
    #pragma unroll
    for (int mf = 0; mf < 13; ++mf) {
        #pragma unroll
        for (int i = 0; i < 4; ++i) {
            int ml = mf * 16 + lg * 4 + i;          // local row = kp
            if (ml < 196) {
                #pragma unroll
                for (int nf = 0; nf < 2; ++nf) {
                    int n = w * 32 + nf * 16 + l15;
                    float v = acc[mf][nf][i];
                    if (n < 128) v += patch_pos[ml * 128 + n];
                    kv[((size_t)b * 196 + ml) * 256 + n] = f2bf(v);
                }
            }
        }
    }
}

// ---------------- kernel 2: per-batch attention ----------------
__global__ __launch_bounds__(1024)
void k_attn(const unsigned short* __restrict__ kv,
            const float* __restrict__ queries,
            const float* __restrict__ prior,
            const float* __restrict__ temperature,
            float* __restrict__ attn_out,
            unsigned short* __restrict__ att)
{
    __shared__ unsigned short k_s[196][136];
    __shared__ unsigned short v_s[196][128];
    __shared__ unsigned short q_s[52][128];
    __shared__ float          l_s[52][196];

    const int b   = blockIdx.x;
    const int tid = threadIdx.x;
    const size_t base = (size_t)b * 196 * 256;

    for (int idx = tid; idx < 6272; idx += 1024) {
        int row = idx >> 5;
        int c   = (idx & 31) * 8;
        bf16x8 v = *reinterpret_cast<const bf16x8*>(kv + base + row * 256 + c);
        if (c < 128) *reinterpret_cast<bf16x8*>(&k_s[row][c])       = v;
        else         *reinterpret_cast<bf16x8*>(&v_s[row][c - 128]) = v;
    }
    for (int idx = tid; idx < 1664; idx += 1024) {
        int row = idx >> 5;
        int c   = (idx & 31) * 4;
        const float* qp = queries + row * 128 + c;
        bf16x4 sv;
        sv[0] = (short)f2bf(qp[0]); sv[1] = (short)f2bf(qp[1]);
        sv[2] = (short)f2bf(qp[2]); sv[3] = (short)f2bf(qp[3]);
        *reinterpret_cast<bf16x4*>(&q_s[row][c]) = sv;
    }
    __syncthreads();

    const float inv_temp  = 1.0f / (log1pf(expf(temperature[0])) + 0.5f);
    const float inv_scale = 0.08838834764831845f;

    for (int task = tid; task < 3328; task += 1024) {
        int q  = task >> 6;
        int kg = task & 63;
        if (kg < 49) {
            float dot0 = 0.f, dot1 = 0.f, dot2 = 0.f, dot3 = 0.f;
            #pragma unroll 4
            for (int c = 0; c < 128; c += 8) {
                bf16x8 qv = *reinterpret_cast<const bf16x8*>(&q_s[q][c]);
                float qf[8];
                #pragma unroll
                for (int e = 0; e < 8; ++e) qf[e] = bf2f_s(qv[e]);
                bf16x8 k0v = *reinterpret_cast<const bf16x8*>(&k_s[kg][c]);
                bf16x8 k1v = *reinterpret_cast<const bf16x8*>(&k_s[kg + 49][c]);
                bf16x8 k2v = *reinterpret_cast<const bf16x8*>(&k_s[kg + 98][c]);
                bf16x8 k3v = *reinterpret_cast<const bf16x8*>(&k_s[kg + 147][c]);
                #pragma unroll
                for (int e = 0; e < 8; ++e) {
                    dot0 += qf[e] * bf2f_s(k0v[e]);
                    dot1 += qf[e] * bf2f_s(k1v[e]);
                    dot2 += qf[e] * bf2f_s(k2v[e]);
                    dot3 += qf[e] * bf2f_s(k3v[e]);
                }
            }
            int k;
            k = kg;       l_s[q][k] = (dot0 * inv_scale + prior[q * 196 + k]) * inv_temp;
            k = kg + 49;  l_s[q][k] = (dot1 * inv_scale + prior[q * 196 + k]) * inv_temp;
            k = kg + 98;  l_s[q][k] = (dot2 * inv_scale + prior[q * 196 + k]) * inv_temp;
            k = kg + 147; l_s[q][k] = (dot3 * inv_scale + prior[q * 196 + k]) * inv_temp;
        }
    }
    __syncthreads();

    const int lane = tid & 63;
    const int wave = tid >> 6;
    for (int q = wave; q < 52; q += 16) {
        float x0 = l_s[q][lane];
        float x1 = l_s[q][lane + 64];
        float x2 = l_s[q][lane + 128];
        float x3 = (lane < 4) ? l_s[q][lane + 192] : -1e30f;
        float m = fmaxf(fmaxf(x0, x1), fmaxf(x2, x3));
        #pragma unroll
        for (int off = 32; off > 0; off >>= 1) m = fmaxf(m, __shfl_xor(m, off));
        float e0 = expf(x0 - m), e1 = expf(x1 - m), e2 = expf(x2 - m);
        float e3 = (lane < 4) ? expf(x3 - m) : 0.0f;
        float s = e0 + e1 + e2 + e3;
        #pragma unroll
        for (int off = 32; off > 0; off >>= 1) s += __shfl_xor(s, off);
        float inv = 1.0f / s;
        float* po = attn_out + ((size_t)b * 52 + q) * 196;
        float a0 = e0 * inv, a1 = e1 * inv, a2 = e2 * inv;
        l_s[q][lane]       = a0;  po[lane]       = a0;
        l_s[q][lane + 64]  = a1;  po[lane + 64]  = a1;
        l_s[q][lane + 128] = a2;  po[lane + 128] = a2;
        if (lane < 4) { float a3 = e3 * inv; l_s[q][lane + 192] = a3; po[lane + 192] = a3; }
    }
    __syncthreads();

    if (tid < 832) {
        int q  = tid >> 4;
        int a0 = (tid & 15) * 8;
        float accv[8] = {0.f, 0.f, 0.f, 0.f, 0.f, 0.f, 0.f, 0.f};
        for (int k = 0; k < 196; ++k) {
            float wgt = l_s[q][k];
            bf16x8 vv = *reinterpret_cast<const bf16x8*>(&v_s[k][a0]);
            #pragma unroll
            for (int e = 0; e < 8; ++e) accv[e] += wgt * bf2f_s(vv[e]);
        }
        bf16x8 sv;
        #pragma unroll
        for (int e = 0; e < 8; ++e) sv[e] = (short)f2bf(accv[e]);
        *reinterpret_cast<bf16x8*>(att + ((size_t)b * 52 + q) * 128 + a0) = sv;
    }
}

// ---------------- kernel 3: output GEMM ----------------
__global__ __launch_bounds__(512)
void k_out(const unsigned short* __restrict__ att,
           const unsigned short* __restrict__ Wob,
           const float* __restrict__ bo,
           float* __restrict__ out)
{
    __shared__ unsigned short As[64][72];
    __shared__ unsigned short Bs[256][72];

    const int tid  = threadIdx.x;
    const int lane = tid & 63;
    const int wave = tid >> 6;
    const int wm   = wave >> 2;
    const int wn   = wave & 3;
    const int l15  = lane & 15;
    const int lg   = lane >> 4;
    const int row0 = blockIdx.x * 64;
    const int e0   = blockIdx.y * 256;

    f32x4 acc[2][4];
    #pragma unroll
    for (int i = 0; i < 2; ++i)
        #pragma unroll
        for (int j = 0; j < 4; ++j)
            acc[i][j] = (f32x4){0.f, 0.f, 0.f, 0.f};

    for (int ko = 0; ko < 128; ko += 64) {
        {
            int r = tid >> 3;
            int c = (tid & 7) * 8;
            bf16x8 v = *reinterpret_cast<const bf16x8*>(att + (size_t)(row0 + r) * 128 + ko + c);
            *reinterpret_cast<bf16x8*>(&As[r][c]) = v;
        }
        {
            int r = tid >> 3;
            int c = (tid & 7) * 8;
            #pragma unroll
            for (int it = 0; it < 4; ++it) {
                bf16x8 v = *reinterpret_cast<const bf16x8*>(Wob + (size_t)(e0 + it * 64 + r) * 128 + ko + c);
                *reinterpret_cast<bf16x8*>(&Bs[it * 64 + r][c]) = v;
            }
        }
        __syncthreads();
        #pragma unroll
        for (int kk = 0; kk < 2; ++kk) {
            bf16x8 af[2], bfr[4];
            #pragma unroll
            for (int mi = 0; mi < 2; ++mi)
                af[mi] = *reinterpret_cast<const bf16x8*>(&As[wm * 32 + mi * 16 + l15][kk * 32 + lg * 8]);
            #pragma unroll
            for (int ni = 0; ni < 4; ++ni)
                bfr[ni] = *reinterpret_cast<const bf16x8*>(&Bs[wn * 64 + ni * 16 + l15][kk * 32 + lg * 8]);
            #pragma unroll
            for (int mi = 0; mi < 2; ++mi)
                #pragma unroll
                for (int ni = 0; ni < 4; ++ni)
                    acc[mi][ni] = __builtin_amdgcn_mfma_f32_16x16x32_bf16(af[mi], bfr[ni], acc[mi][ni], 0, 0, 0);
        }
        __syncthreads();
    }
    #pragma unroll
    for (int mi = 0; mi < 2; ++mi) {
        #pragma unroll
        for (int i = 0; i < 4; ++i) {
            int m = row0 + wm * 32 + mi * 16 + lg * 4 + i;
            #pragma unroll
            for (int ni = 0; ni < 4; ++ni) {
                int e = e0 + wn * 64 + ni * 16 + l15;
                out[(size_t)m * 1024 + e] = acc[mi][ni][i] + bo[e];
            }
        }
    }
}

extern "C" void kernel_launch(void* const* d_in, const int* in_sizes, int n_in,
                              void* d_out, int out_size, void* d_ws, size_t ws_size,
                              hipStream_t stream)
{
    const float* patches     = (const float*)d_in[0];   // [256][196][1024]
    const float* queries     = (const float*)d_in[1];   // [52][128]
    const float* Wk          = (const float*)d_in[2];   // [128][1024]
    const float* Wv          = (const float*)d_in[3];   // [128][1024]
    const float* Wo          = (const float*)d_in[4];   // [1024][128]
    const float* bo          = (const float*)d_in[5];   // [1024]
    const float* patch_pos   = (const float*)d_in[6];   // [196][128]
    const float* temperature = (const float*)d_in[7];   // [1]
    const float* prior       = (const float*)d_in[8];   // [52][196]

    float* out      = (float*)d_out;                    // [256*52][1024]
    float* attn_out = out + (size_t)256 * 52 * 1024;    // [256*52][196]

    unsigned short* Wkvb = (unsigned short*)d_ws;              // 256*1024
    unsigned short* Wob  = Wkvb + 256 * 1024;                  // 1024*128
    unsigned short* kv   = Wob + 1024 * 128;                   // 50176*256
    unsigned short* att  = kv + (size_t)50176 * 256;           // 13312*128

    k_convert <<<128, 256, 0, stream>>>(Wk, Wv, Wo, Wkvb, Wob);
    k_keysvals<<<256, 512, 0, stream>>>(patches, Wkvb, patch_pos, kv);
    k_attn    <<<256, 1024, 0, stream>>>(kv, queries, prior, temperature, attn_out, att);
    k_out     <<<dim3(208, 4), 512, 0, stream>>>(att, Wob, bo, out);
}